// Round 8
// baseline (1384.296 us; speedup 1.0000x reference)
//
#include <hip/hip_runtime.h>
#include <math.h>

#define N 16384
#define D 1024
#define EPSF 1e-8f
#define QSCALE 448.0f
#define NPAIRS 2080
#define PANB 262144 /* bytes per 256-row i8 panel */

typedef __attribute__((ext_vector_type(4))) int i32x4;
typedef unsigned int u32;
typedef unsigned long long u64;

// LDS: ring-2 of (A 16K + B 16K) = 64 KB, + 128 B control => 2 blocks/CU
#define LDS_TOT 65664

__device__ __forceinline__ void gload_lds16(const void* g, void* l) {
  __builtin_amdgcn_global_load_lds(
      (const __attribute__((address_space(1))) u32*)g,
      (__attribute__((address_space(3))) u32*)l, 16, 0, 0);
}

__device__ __forceinline__ u64 maxu64(u64 x, u64 y) { return x > y ? x : y; }

__device__ __forceinline__ void decode_pair(int t, int& a, int& b) {
  int aa = (int)((129.0 - sqrt(129.0 * 129.0 - 8.0 * (double)t)) * 0.5);
  if (aa < 0) aa = 0;
  if (aa > 63) aa = 63;
  while (((aa + 1) * 64 - ((aa + 1) * aa) / 2) <= t) ++aa;
  while ((aa * 64 - (aa * (aa - 1)) / 2) > t) --aa;
  a = aa;
  b = aa + (t - (aa * 64 - (aa * (aa - 1)) / 2));
}

// ---------- kernel 1: norms + globally-scaled i8 matrix + zero best/ctr ----------

__global__ __launch_bounds__(256) void k_normalize(
    const float* __restrict__ x, signed char* __restrict__ xq,
    float* __restrict__ norms, u64* __restrict__ best, int* __restrict__ ctr) {
  const int w = threadIdx.x >> 6, lane = threadIdx.x & 63;
  const int i = blockIdx.x * 4 + w;  // one wave per row
  if (threadIdx.x < 4) best[(size_t)blockIdx.x * 4 + threadIdx.x] = 0;
  if (blockIdx.x == 0 && threadIdx.x == 0) *ctr = 0;
  const float4* xi = (const float4*)(x + (size_t)i * D);
  float4 v[4];
  float s = 0.f;
#pragma unroll
  for (int t = 0; t < 4; ++t) {
    v[t] = xi[lane + t * 64];
    s += v[t].x * v[t].x + v[t].y * v[t].y + v[t].z * v[t].z + v[t].w * v[t].w;
  }
#pragma unroll
  for (int sh = 32; sh; sh >>= 1) s += __shfl_xor(s, sh, 64);
  const float nrm = sqrtf(s);
  if (lane == 0) norms[i] = nrm;
  const float qs = QSCALE / fmaxf(nrm, EPSF);  // global scale: q = xn*QSCALE
  u32* xo = (u32*)(xq + (size_t)i * D);
#pragma unroll
  for (int t = 0; t < 4; ++t) {
    const int q0 = __float2int_rn(fminf(fmaxf(v[t].x * qs, -127.f), 127.f));
    const int q1 = __float2int_rn(fminf(fmaxf(v[t].y * qs, -127.f), 127.f));
    const int q2 = __float2int_rn(fminf(fmaxf(v[t].z * qs, -127.f), 127.f));
    const int q3 = __float2int_rn(fminf(fmaxf(v[t].w * qs, -127.f), 127.f));
    xo[lane + t * 64] = (u32)(q0 & 0xff) | ((u32)(q1 & 0xff) << 8) |
                        ((u32)(q2 & 0xff) << 16) | ((u32)(q3 & 0xff) << 24);
  }
}

// ---------- kernel 2: work-stealing symmetric-pair i8 MFMA argmax ----------
// 512 blocks (2/CU via 64KB LDS), 512 thr = 8 waves (4M x 2N), per-wave C =
// 64x128. Each stolen pair = one 256x256 tile (a<=b), 16 K-tiles of 64 k.
// Ring-2 double buffer, stage k+1 at iter top, vmcnt(0)+barrier per K-tile;
// cross-pair: k=15 stages next stolen pair's k0 (lookahead steal). Row-side
// and col-side argmax both published via deterministic u64 atomicMax.

#define SG(gaddr, daddr) \
  gload_lds16(xqB + (gaddr) + srcLane, lds + (daddr) + w * 1024)

#define KT2(K_)                                                                \
  {                                                                            \
    const int rB = ((K_)&1) * 32768;                                           \
    const int sB = (((K_) + 1) & 1) * 32768;                                   \
    if ((K_) < 15) {                                                           \
      const size_t aG = aPan + (size_t)(((K_) + 1) * 64);                      \
      const size_t bG = bPan + (size_t)(((K_) + 1) * 64);                      \
      SG(aG, sB);                                                              \
      SG(aG + 131072, sB + 8192);                                              \
      SG(bG, sB + 16384);                                                      \
      SG(bG + 131072, sB + 24576);                                             \
    } else if (hasNext) {                                                      \
      SG(aPanN, sB);                                                           \
      SG(aPanN + 131072, sB + 8192);                                           \
      SG(bPanN, sB + 16384);                                                   \
      SG(bPanN + 131072, sB + 24576);                                          \
    }                                                                          \
    i32x4 aa[4], bb[4];                                                        \
    _Pragma("unroll") for (int m = 0; m < 4; ++m) aa[m] =                      \
        *(const i32x4*)(lds + rB + aOff[m]);                                   \
    _Pragma("unroll") for (int n = 0; n < 4; ++n) bb[n] =                      \
        *(const i32x4*)(lds + rB + bOff[n]);                                   \
    __builtin_amdgcn_s_setprio(1);                                             \
    _Pragma("unroll") for (int m = 0; m < 4; ++m)                              \
      _Pragma("unroll") for (int n = 0; n < 4; ++n)                            \
        acc[m][n] = __builtin_amdgcn_mfma_i32_16x16x64_i8(aa[m], bb[n],        \
                                                          acc[m][n], 0, 0, 0); \
    __builtin_amdgcn_s_setprio(0);                                             \
    _Pragma("unroll") for (int n = 0; n < 4; ++n) bb[n] =                      \
        *(const i32x4*)(lds + rB + bOff[4 + n]);                               \
    __builtin_amdgcn_s_setprio(1);                                             \
    _Pragma("unroll") for (int m = 0; m < 4; ++m)                              \
      _Pragma("unroll") for (int n = 0; n < 4; ++n)                            \
        acc[m][4 + n] = __builtin_amdgcn_mfma_i32_16x16x64_i8(                 \
            aa[m], bb[n], acc[m][4 + n], 0, 0, 0);                             \
    __builtin_amdgcn_s_setprio(0);                                             \
    asm volatile("s_waitcnt vmcnt(0)" ::: "memory");                           \
    __builtin_amdgcn_s_barrier();                                              \
    asm volatile("" ::: "memory");                                             \
  }

__global__ __launch_bounds__(512, 4) void k_argmax(
    const signed char* __restrict__ xq, u64* __restrict__ best,
    int* __restrict__ ctr) {
  extern __shared__ char lds[];
  int* s_next = (int*)(lds + 65536);  // 2 parity slots
  const char* xqB = (const char*)xq;
  const int tid = (int)threadIdx.x, lane = tid & 63, w = tid >> 6;
  const int wr = w >> 1, wc = w & 1;

  // LDS region (16KB per panel): 256 rows x 64B, 2 rows per 128B line,
  // granule swizzle: inner = (((rr&1)<<6)|(q<<4)) ^ ((line&7)<<4)
  int aOff[4], bOff[8];
  const int q = lane >> 4, li = lane & 15;
#pragma unroll
  for (int m = 0; m < 4; ++m) {
    const int rr = wr * 64 + m * 16 + li;
    const int line = rr >> 1;
    aOff[m] = line * 128 + ((((rr & 1) << 6) | (q << 4)) ^ ((line & 7) << 4));
  }
#pragma unroll
  for (int nf = 0; nf < 8; ++nf) {
    const int rr = wc * 128 + nf * 16 + li;
    const int line = rr >> 1;
    bOff[nf] = 16384 + line * 128 +
               ((((rr & 1) << 6) | (q << 4)) ^ ((line & 7) << 4));
  }
  // staging per-lane source offset (inverse swizzle; linear gload dest)
  const int posx = (lane & 7) ^ (lane >> 3);
  const int rrl = ((w * 8 + (lane >> 3)) << 1) | (posx >> 2);
  const int srcLane = rrl * 1024 + (posx & 3) * 16;

  const int rB2 = wr * 64 + (q << 2);
  const int cB2 = wc * 128 + li;

  // bootstrap: steal first two pairs
  if (tid == 0) {
    s_next[0] = atomicAdd(ctr, 1);
    s_next[1] = atomicAdd(ctr, 1);
  }
  __syncthreads();
  int pcur = s_next[0], pnext = s_next[1];
  __syncthreads();  // all read before slot reuse
  if (pcur >= NPAIRS) return;

  int a, b;
  decode_pair(pcur, a, b);
  size_t aPan = (size_t)a * PANB, bPan = (size_t)b * PANB;
  // stage pair0 k0 into buf0
  SG(aPan, 0);
  SG(aPan + 131072, 8192);
  SG(bPan, 16384);
  SG(bPan + 131072, 24576);
  asm volatile("s_waitcnt vmcnt(0)" ::: "memory");
  __syncthreads();

  int par = 0;
  i32x4 acc[4][8];
  while (true) {
    const bool hasNext = (pnext < NPAIRS);
    int an = 0, bn = 0;
    if (hasNext) decode_pair(pnext, an, bn);
    const size_t aPanN = (size_t)an * PANB, bPanN = (size_t)bn * PANB;
    if (tid == 0) s_next[par] = atomicAdd(ctr, 1);  // steal pair-after-next

#pragma unroll
    for (int m = 0; m < 4; ++m)
#pragma unroll
      for (int n = 0; n < 8; ++n) acc[m][n] = (i32x4){0, 0, 0, 0};

    KT2(0); KT2(1); KT2(2); KT2(3);
    KT2(4); KT2(5); KT2(6); KT2(7);
    KT2(8); KT2(9); KT2(10); KT2(11);
    KT2(12); KT2(13); KT2(14); KT2(15);

    // ---- epilogue for pair (a,b) ----
    const int aBase = a * 256, colBase = b * 256;
    // row-side: rows of a over cols of b
#pragma unroll
    for (int m = 0; m < 4; ++m)
#pragma unroll
      for (int r = 0; r < 4; ++r) {
        const int rl = rB2 + m * 16 + r;
        int pm = (int)0x80000000;
        if (a == b) {
#pragma unroll
          for (int nf = 0; nf < 8; ++nf) {
            int pv = (int)(((u32)acc[m][nf][r] << 3) | (u32)nf);
            if (rl == cB2 + nf * 16) pv = (int)0x80000000;
            pm = pm > pv ? pm : pv;
          }
        } else {
#pragma unroll
          for (int nf = 0; nf < 8; ++nf) {
            const int pv = (int)(((u32)acc[m][nf][r] << 3) | (u32)nf);
            pm = pm > pv ? pm : pv;
          }
        }
        const u32 mono = (u32)(pm >> 3) ^ 0x80000000u;
        u64 p = ((u64)mono << 32) | (u32)(colBase + cB2 + ((pm & 7) << 4));
#pragma unroll
        for (int sh = 1; sh < 16; sh <<= 1)
          p = maxu64(p, __shfl_xor(p, sh, 64));
        if (li == 0) atomicMax(best + (aBase + rl), p);
      }

    // col-side: rows of b, candidates = rows of a (skip on diagonal)
    if (a != b) {
#pragma unroll
      for (int nf = 0; nf < 8; ++nf) {
        int pv = (int)0x80000000;
#pragma unroll
        for (int m = 0; m < 4; ++m)
#pragma unroll
          for (int r = 0; r < 4; ++r) {
            const int c =
                (int)(((u32)acc[m][nf][r] << 6) | (u32)(m * 16 + q * 4 + r));
            pv = pv > c ? pv : c;
          }
        {
          const int o1 = __shfl_xor(pv, 16, 64);
          pv = pv > o1 ? pv : o1;
          const int o2 = __shfl_xor(pv, 32, 64);
          pv = pv > o2 ? pv : o2;
        }
        if (q == 0) {
          const int dot = pv >> 6;
          const int grow = aBase + wr * 64 + (pv & 63);
          const u64 pk = ((u64)((u32)dot ^ 0x80000000u) << 32) | (u32)grow;
          atomicMax(best + (colBase + cB2 + nf * 16), pk);
        }
      }
    }

    const int pnn = s_next[par];  // published by the 16 KT barriers
    if (!hasNext) break;
    pcur = pnext;
    a = an; b = bn;
    aPan = aPanN; bPan = bPanN;
    pnext = pnn;
    par ^= 1;
  }
}

// ---------- kernel 3: exact fp32 distance + log ----------

__global__ __launch_bounds__(256) void k_dist(
    const float* __restrict__ x, const float* __restrict__ norms,
    const u64* __restrict__ best, float* __restrict__ logd) {
  const int w = threadIdx.x >> 6, lane = threadIdx.x & 63;
  const int i = blockIdx.x * 4 + w;
  const u64 p = best[i];
  const int j = (int)(p & 0xffffffffu);
  const float invi = 1.f / fmaxf(norms[i], EPSF);
  const float invj = 1.f / fmaxf(norms[j], EPSF);
  const float4* xi = (const float4*)(x + (size_t)i * D);
  const float4* xj = (const float4*)(x + (size_t)j * D);
  float s = 0.f;
#pragma unroll
  for (int t = 0; t < 4; ++t) {
    const float4 av = xi[lane + t * 64], bv = xj[lane + t * 64];
    float d;
    d = av.x * invi - bv.x * invj + EPSF; s += d * d;
    d = av.y * invi - bv.y * invj + EPSF; s += d * d;
    d = av.z * invi - bv.z * invj + EPSF; s += d * d;
    d = av.w * invi - bv.w * invj + EPSF; s += d * d;
  }
#pragma unroll
  for (int sh = 32; sh; sh >>= 1) s += __shfl_xor(s, sh, 64);
  if (lane == 0) logd[i] = logf(sqrtf(s) + EPSF);
}

// ---------- kernel 4: deterministic fixed-order mean ----------

__global__ __launch_bounds__(256) void k_final(const float* __restrict__ logd,
                                               float* __restrict__ out) {
  __shared__ double red[256];
  double s = 0.0;
  for (int i = threadIdx.x; i < N; i += 256) s += (double)logd[i];
  red[threadIdx.x] = s;
  __syncthreads();
  for (int sh = 128; sh; sh >>= 1) {
    if ((int)threadIdx.x < sh) red[threadIdx.x] += red[threadIdx.x + sh];
    __syncthreads();
  }
  if (threadIdx.x == 0) out[0] = (float)(-red[0] / (double)N);
}

// ---------- launch ----------

extern "C" void kernel_launch(void* const* d_in, const int* in_sizes, int n_in,
                              void* d_out, int out_size, void* d_ws,
                              size_t ws_size, hipStream_t stream) {
  const float* x = (const float*)d_in[0];
  float* out = (float*)d_out;
  char* ws = (char*)d_ws;

  // ws: xq 16MB | norms 64KB | best N*8 = 128KB | logd 64KB | ctr 64B
  signed char* xq = (signed char*)ws;
  float* norms = (float*)(ws + 16777216);
  u64* best = (u64*)(ws + 16842752);
  float* logd = (float*)(ws + 16973824);
  int* ctr = (int*)(ws + 17039360);

  k_normalize<<<N / 4, 256, 0, stream>>>(x, xq, norms, best, ctr);
  k_argmax<<<512, 512, LDS_TOT, stream>>>(xq, best, ctr);
  k_dist<<<N / 4, 256, 0, stream>>>(x, norms, best, logd);
  k_final<<<1, 256, 0, stream>>>(logd, out);
}

// Round 9
// 252.860 us; speedup vs baseline: 5.4745x; 5.4745x over previous
//
#include <hip/hip_runtime.h>
#include <math.h>

#define N 16384
#define D 1024
#define EPSF 1e-8f
#define QSCALE 448.0f
#define NPAIRS 2080
#define PANB 262144 /* bytes per 256-row i8 panel */

typedef __attribute__((ext_vector_type(4))) int i32x4;
typedef unsigned int u32;
typedef unsigned long long u64;

// LDS: A ring4 [0,64K), B ring4 [64K,128K), s_next [128K,+16B)
#define LDS_Bb 65536
#define LDS_TOT 131088

__device__ __forceinline__ void gload_lds16(const void* g, void* l) {
  __builtin_amdgcn_global_load_lds(
      (const __attribute__((address_space(1))) u32*)g,
      (__attribute__((address_space(3))) u32*)l, 16, 0, 0);
}

__device__ __forceinline__ u64 maxu64(u64 x, u64 y) { return x > y ? x : y; }

__device__ __forceinline__ void decode_pair(int t, int& a, int& b) {
  int aa = (int)((129.0 - sqrt(129.0 * 129.0 - 8.0 * (double)t)) * 0.5);
  if (aa < 0) aa = 0;
  if (aa > 63) aa = 63;
  while (((aa + 1) * 64 - ((aa + 1) * aa) / 2) <= t) ++aa;
  while ((aa * 64 - (aa * (aa - 1)) / 2) > t) --aa;
  a = aa;
  b = aa + (t - (aa * 64 - (aa * (aa - 1)) / 2));
}

// ---------- kernel 1: norms + globally-scaled i8 matrix + zero best/ctr ----------

__global__ __launch_bounds__(256) void k_normalize(
    const float* __restrict__ x, signed char* __restrict__ xq,
    float* __restrict__ norms, u64* __restrict__ best, int* __restrict__ ctr) {
  const int w = threadIdx.x >> 6, lane = threadIdx.x & 63;
  const int i = blockIdx.x * 4 + w;  // one wave per row
  if (threadIdx.x < 4) best[(size_t)blockIdx.x * 4 + threadIdx.x] = 0;
  if (blockIdx.x == 0 && threadIdx.x == 0) *ctr = 0;
  const float4* xi = (const float4*)(x + (size_t)i * D);
  float4 v[4];
  float s = 0.f;
#pragma unroll
  for (int t = 0; t < 4; ++t) {
    v[t] = xi[lane + t * 64];
    s += v[t].x * v[t].x + v[t].y * v[t].y + v[t].z * v[t].z + v[t].w * v[t].w;
  }
#pragma unroll
  for (int sh = 32; sh; sh >>= 1) s += __shfl_xor(s, sh, 64);
  const float nrm = sqrtf(s);
  if (lane == 0) norms[i] = nrm;
  const float qs = QSCALE / fmaxf(nrm, EPSF);  // global scale: q = xn*QSCALE
  u32* xo = (u32*)(xq + (size_t)i * D);
#pragma unroll
  for (int t = 0; t < 4; ++t) {
    const int q0 = __float2int_rn(fminf(fmaxf(v[t].x * qs, -127.f), 127.f));
    const int q1 = __float2int_rn(fminf(fmaxf(v[t].y * qs, -127.f), 127.f));
    const int q2 = __float2int_rn(fminf(fmaxf(v[t].z * qs, -127.f), 127.f));
    const int q3 = __float2int_rn(fminf(fmaxf(v[t].w * qs, -127.f), 127.f));
    xo[lane + t * 64] = (u32)(q0 & 0xff) | ((u32)(q1 & 0xff) << 8) |
                        ((u32)(q2 & 0xff) << 16) | ((u32)(q3 & 0xff) << 24);
  }
}

// ---------- kernel 2: work-stealing symmetric-pair i8 MFMA argmax ----------
// 256 blocks (1/CU), 512 thr = 8 waves (4M x 2N), per-wave C = 64x128.
// Each stolen pair = one 256x256 tile (a<=b), 16 K-tiles of 64 k.
// Ring-4 LDS, stage 3 K-tiles ahead (rolling into the NEXT stolen pair's
// tiles 0..2 at k=13..15), 1 barrier + counted vmcnt(8) per K-tile.
// Row- and col-side argmax published via deterministic u64 atomicMax.

#define SG(gaddr, daddr) \
  gload_lds16(xqB + (gaddr) + srcLane, lds + (daddr) + w * 1024)

#define KT1(K_)                                                                \
  {                                                                            \
    __builtin_amdgcn_s_barrier();                                              \
    asm volatile("" ::: "memory");                                             \
    if ((K_) < 13) {                                                           \
      const size_t aG = aPan + (size_t)(((K_) + 3) * 64);                      \
      const size_t bG = bPan + (size_t)(((K_) + 3) * 64);                      \
      SG(aG, (((K_) + 3) & 3) * 16384);                                        \
      SG(aG + 131072, (((K_) + 3) & 3) * 16384 + 8192);                        \
      SG(bG, LDS_Bb + (((K_) + 3) & 3) * 16384);                               \
      SG(bG + 131072, LDS_Bb + (((K_) + 3) & 3) * 16384 + 8192);               \
    } else if (hasNext) {                                                      \
      const size_t aG = aPanN + (size_t)(((K_)-13) * 64);                      \
      const size_t bG = bPanN + (size_t)(((K_)-13) * 64);                      \
      SG(aG, (((K_) + 3) & 3) * 16384);                                        \
      SG(aG + 131072, (((K_) + 3) & 3) * 16384 + 8192);                        \
      SG(bG, LDS_Bb + (((K_) + 3) & 3) * 16384);                               \
      SG(bG + 131072, LDS_Bb + (((K_) + 3) & 3) * 16384 + 8192);               \
    }                                                                          \
    i32x4 aa[4], bb[4];                                                        \
    _Pragma("unroll") for (int m = 0; m < 4; ++m) aa[m] =                      \
        *(const i32x4*)(lds + ((K_)&3) * 16384 + aOff[m]);                     \
    _Pragma("unroll") for (int n = 0; n < 4; ++n) bb[n] =                      \
        *(const i32x4*)(lds + LDS_Bb + ((K_)&3) * 16384 + bOff[n]);            \
    __builtin_amdgcn_s_setprio(1);                                             \
    _Pragma("unroll") for (int m = 0; m < 4; ++m)                              \
      _Pragma("unroll") for (int n = 0; n < 4; ++n)                            \
        acc[m][n] = __builtin_amdgcn_mfma_i32_16x16x64_i8(aa[m], bb[n],        \
                                                          acc[m][n], 0, 0, 0); \
    __builtin_amdgcn_s_setprio(0);                                             \
    _Pragma("unroll") for (int n = 0; n < 4; ++n) bb[n] =                      \
        *(const i32x4*)(lds + LDS_Bb + ((K_)&3) * 16384 + bOff[4 + n]);        \
    __builtin_amdgcn_s_setprio(1);                                             \
    _Pragma("unroll") for (int m = 0; m < 4; ++m)                              \
      _Pragma("unroll") for (int n = 0; n < 4; ++n)                            \
        acc[m][4 + n] = __builtin_amdgcn_mfma_i32_16x16x64_i8(                 \
            aa[m], bb[n], acc[m][4 + n], 0, 0, 0);                             \
    __builtin_amdgcn_s_setprio(0);                                             \
    asm volatile("s_waitcnt vmcnt(8)" ::: "memory");                           \
  }

__global__ __launch_bounds__(512, 2) void k_argmax(
    const signed char* __restrict__ xq, u64* __restrict__ best,
    int* __restrict__ ctr) {
  extern __shared__ char lds[];
  int* s_next = (int*)(lds + 131072);  // 2 parity slots
  const char* xqB = (const char*)xq;
  const int tid = (int)threadIdx.x, lane = tid & 63, w = tid >> 6;
  const int wr = w >> 1, wc = w & 1;

  // LDS region (16KB per panel): 256 rows x 64B, 2 rows per 128B line,
  // granule swizzle: inner = (((rr&1)<<6)|(q<<4)) ^ ((line&7)<<4)
  int aOff[4], bOff[8];
  const int q = lane >> 4, li = lane & 15;
#pragma unroll
  for (int m = 0; m < 4; ++m) {
    const int rr = wr * 64 + m * 16 + li;
    const int line = rr >> 1;
    aOff[m] = line * 128 + ((((rr & 1) << 6) | (q << 4)) ^ ((line & 7) << 4));
  }
#pragma unroll
  for (int nf = 0; nf < 8; ++nf) {
    const int rr = wc * 128 + nf * 16 + li;
    const int line = rr >> 1;
    bOff[nf] = line * 128 + ((((rr & 1) << 6) | (q << 4)) ^ ((line & 7) << 4));
  }
  // staging per-lane source offset (inverse swizzle; linear gload dest)
  const int posx = (lane & 7) ^ (lane >> 3);
  const int rrl = ((w * 8 + (lane >> 3)) << 1) | (posx >> 2);
  const int srcLane = rrl * 1024 + (posx & 3) * 16;

  const int rB2 = wr * 64 + (q << 2);
  const int cB2 = wc * 128 + li;

  // bootstrap: steal first two pairs
  if (tid == 0) {
    s_next[0] = atomicAdd(ctr, 1);
    s_next[1] = atomicAdd(ctr, 1);
  }
  __syncthreads();
  int pcur = s_next[0], pnext = s_next[1];
  __syncthreads();
  if (pcur >= NPAIRS) return;

  int a, b;
  decode_pair(pcur, a, b);
  size_t aPan = (size_t)a * PANB, bPan = (size_t)b * PANB;
  // prologue: stage K-tiles 0..2 into ring slots 0..2 (12 loads/wave)
  for (int p = 0; p < 3; ++p) {
    SG(aPan + (size_t)(p * 64), p * 16384);
    SG(aPan + (size_t)(p * 64) + 131072, p * 16384 + 8192);
    SG(bPan + (size_t)(p * 64), LDS_Bb + p * 16384);
    SG(bPan + (size_t)(p * 64) + 131072, LDS_Bb + p * 16384 + 8192);
  }
  asm volatile("s_waitcnt vmcnt(8)" ::: "memory");

  int par = 0;
  i32x4 acc[4][8];
  while (true) {
    const bool hasNext = (pnext < NPAIRS);
    int an = 0, bn = 0;
    if (hasNext) decode_pair(pnext, an, bn);
    const size_t aPanN = (size_t)an * PANB, bPanN = (size_t)bn * PANB;
    if (tid == 0) s_next[par] = atomicAdd(ctr, 1);  // steal pair-after-next

#pragma unroll
    for (int m = 0; m < 4; ++m)
#pragma unroll
      for (int n = 0; n < 8; ++n) acc[m][n] = (i32x4){0, 0, 0, 0};

    KT1(0); KT1(1); KT1(2); KT1(3);
    KT1(4); KT1(5); KT1(6); KT1(7);
    KT1(8); KT1(9); KT1(10); KT1(11);
    KT1(12); KT1(13); KT1(14); KT1(15);

    // ---- epilogue for pair (a,b): register folds + atomicMax publish ----
    const int aBase = a * 256, colBase = b * 256;
    // row-side: rows of a over cols of b
#pragma unroll
    for (int m = 0; m < 4; ++m)
#pragma unroll
      for (int r = 0; r < 4; ++r) {
        const int rl = rB2 + m * 16 + r;
        int pm = (int)0x80000000;
        if (a == b) {
#pragma unroll
          for (int nf = 0; nf < 8; ++nf) {
            int pv = (int)(((u32)acc[m][nf][r] << 3) | (u32)nf);
            if (rl == cB2 + nf * 16) pv = (int)0x80000000;
            pm = pm > pv ? pm : pv;
          }
        } else {
#pragma unroll
          for (int nf = 0; nf < 8; ++nf) {
            const int pv = (int)(((u32)acc[m][nf][r] << 3) | (u32)nf);
            pm = pm > pv ? pm : pv;
          }
        }
        const u32 mono = (u32)(pm >> 3) ^ 0x80000000u;
        u64 p = ((u64)mono << 32) | (u32)(colBase + cB2 + ((pm & 7) << 4));
#pragma unroll
        for (int sh = 1; sh < 16; sh <<= 1)
          p = maxu64(p, __shfl_xor(p, sh, 64));
        if (li == 0) atomicMax(best + (aBase + rl), p);
      }

    // col-side: rows of b, candidates = rows of a (skip on diagonal)
    if (a != b) {
#pragma unroll
      for (int nf = 0; nf < 8; ++nf) {
        int pv = (int)0x80000000;
#pragma unroll
        for (int m = 0; m < 4; ++m)
#pragma unroll
          for (int r = 0; r < 4; ++r) {
            const int c =
                (int)(((u32)acc[m][nf][r] << 6) | (u32)(m * 16 + q * 4 + r));
            pv = pv > c ? pv : c;
          }
        {
          const int o1 = __shfl_xor(pv, 16, 64);
          pv = pv > o1 ? pv : o1;
          const int o2 = __shfl_xor(pv, 32, 64);
          pv = pv > o2 ? pv : o2;
        }
        if (q == 0) {
          const int dot = pv >> 6;
          const int grow = aBase + wr * 64 + (pv & 63);
          const u64 pk = ((u64)((u32)dot ^ 0x80000000u) << 32) | (u32)grow;
          atomicMax(best + (colBase + cB2 + nf * 16), pk);
        }
      }
    }

    if (!hasNext) break;
    const int pnn = s_next[par];  // published by the 16 KT barriers
    pcur = pnext;
    a = an; b = bn;
    aPan = aPanN; bPan = bPanN;
    pnext = pnn;
    par ^= 1;
  }
}

// ---------- kernel 3: exact fp32 distance + log ----------

__global__ __launch_bounds__(256) void k_dist(
    const float* __restrict__ x, const float* __restrict__ norms,
    const u64* __restrict__ best, float* __restrict__ logd) {
  const int w = threadIdx.x >> 6, lane = threadIdx.x & 63;
  const int i = blockIdx.x * 4 + w;
  const u64 p = best[i];
  const int j = (int)(p & 0xffffffffu);
  const float invi = 1.f / fmaxf(norms[i], EPSF);
  const float invj = 1.f / fmaxf(norms[j], EPSF);
  const float4* xi = (const float4*)(x + (size_t)i * D);
  const float4* xj = (const float4*)(x + (size_t)j * D);
  float s = 0.f;
#pragma unroll
  for (int t = 0; t < 4; ++t) {
    const float4 av = xi[lane + t * 64], bv = xj[lane + t * 64];
    float d;
    d = av.x * invi - bv.x * invj + EPSF; s += d * d;
    d = av.y * invi - bv.y * invj + EPSF; s += d * d;
    d = av.z * invi - bv.z * invj + EPSF; s += d * d;
    d = av.w * invi - bv.w * invj + EPSF; s += d * d;
  }
#pragma unroll
  for (int sh = 32; sh; sh >>= 1) s += __shfl_xor(s, sh, 64);
  if (lane == 0) logd[i] = logf(sqrtf(s) + EPSF);
}

// ---------- kernel 4: deterministic fixed-order mean ----------

__global__ __launch_bounds__(256) void k_final(const float* __restrict__ logd,
                                               float* __restrict__ out) {
  __shared__ double red[256];
  double s = 0.0;
  for (int i = threadIdx.x; i < N; i += 256) s += (double)logd[i];
  red[threadIdx.x] = s;
  __syncthreads();
  for (int sh = 128; sh; sh >>= 1) {
    if ((int)threadIdx.x < sh) red[threadIdx.x] += red[threadIdx.x + sh];
    __syncthreads();
  }
  if (threadIdx.x == 0) out[0] = (float)(-red[0] / (double)N);
}

// ---------- launch ----------

extern "C" void kernel_launch(void* const* d_in, const int* in_sizes, int n_in,
                              void* d_out, int out_size, void* d_ws,
                              size_t ws_size, hipStream_t stream) {
  const float* x = (const float*)d_in[0];
  float* out = (float*)d_out;
  char* ws = (char*)d_ws;

  // ws: xq 16MB | norms 64KB | best N*8 = 128KB | logd 64KB | ctr 64B
  signed char* xq = (signed char*)ws;
  float* norms = (float*)(ws + 16777216);
  u64* best = (u64*)(ws + 16842752);
  float* logd = (float*)(ws + 16973824);
  int* ctr = (int*)(ws + 17039360);

  k_normalize<<<N / 4, 256, 0, stream>>>(x, xq, norms, best, ctr);
  k_argmax<<<256, 512, LDS_TOT, stream>>>(xq, best, ctr);
  k_dist<<<N / 4, 256, 0, stream>>>(x, norms, best, logd);
  k_final<<<1, 256, 0, stream>>>(logd, out);
}